// Round 5
// baseline (729.055 us; speedup 1.0000x reference)
//
#include <hip/hip_runtime.h>
#include <math.h>

typedef unsigned short u16;
typedef unsigned int u32;
typedef __attribute__((ext_vector_type(8))) short short8;
typedef __attribute__((ext_vector_type(4))) float f32x4;
typedef __attribute__((ext_vector_type(16))) float f32x16;

__device__ __forceinline__ float b2f(u16 u) {
    return __uint_as_float(((u32)u) << 16);
}
__device__ __forceinline__ u16 f2b(float f) {
    u32 x = __float_as_uint(f);
    return (u16)((x + 0x7fffu + ((x >> 16) & 1u)) >> 16);   // RNE
}
__device__ __forceinline__ float ldext(const void* p, size_t i, int isbf) {
    return isbf ? b2f(((const u16*)p)[i]) : ((const float*)p)[i];
}
__device__ __forceinline__ void stext(void* p, size_t i, int isbf, float v) {
    if (isbf) ((u16*)p)[i] = f2b(v);
    else ((float*)p)[i] = v;
}
// unpack 8 bf16 (uint4) -> 8 f32
__device__ __forceinline__ void unpack8(uint4 w, float* f) {
    const u32* pw = (const u32*)&w;
#pragma unroll
    for (int k = 0; k < 4; ++k) {
        f[2 * k]     = __uint_as_float(pw[k] << 16);
        f[2 * k + 1] = __uint_as_float(pw[k] & 0xffff0000u);
    }
}

// ---------- dtype detector: 1 if h is bf16, 0 if f32 ----------
__global__ void detect_k(const void* __restrict__ h, int* __restrict__ flag) {
    __shared__ int cnt;
    if (threadIdx.x == 0) cnt = 0;
    __syncthreads();
    const u16* p = (const u16*)h;
    int local = 0;
    for (int i = threadIdx.x; i < 4096; i += 256) {
        int e = (p[i] >> 7) & 0xFF;
        if (e != 0 && (e < 110 || e > 133)) local++;
    }
    atomicAdd(&cnt, local);
    __syncthreads();
    if (threadIdx.x == 0) *flag = (cnt < 256) ? 1 : 0;
}

// ---------- transpose ext weight -> bf16 [C][R] ----------
__global__ void transpose_k(const void* __restrict__ src, u16* __restrict__ dst,
                            int R, int C, const int* __restrict__ flag) {
    int isbf = *flag;
    int idx = blockIdx.x * 256 + threadIdx.x;
    if (idx >= R * C) return;
    int r = idx / C, c = idx - r * C;
    dst[c * R + r] = f2b(ldext(src, idx, isbf));
}

// ---------- arsinh norm: y = w[c]*asinh(x)+b[c]; in: ext or forced-bf16; out bf16 ----------
__global__ void norm_k(const void* __restrict__ xb, size_t xoff,
                       const void* __restrict__ w, const void* __restrict__ b,
                       u16* __restrict__ y, const int* __restrict__ flag, int force_bf) {
    int isbf = *flag;
    int xisbf = force_bf ? 1 : isbf;
    size_t base = ((size_t)blockIdx.x * 256 + threadIdx.x) * 4;
    int c0 = (int)(base & 255);
    float v[4];
    if (xisbf) {
        uint2 raw = *reinterpret_cast<const uint2*>((const u16*)xb + xoff + base);
        const u16* px = reinterpret_cast<const u16*>(&raw);
#pragma unroll
        for (int j = 0; j < 4; ++j) v[j] = b2f(px[j]);
    } else {
        float4 r = *reinterpret_cast<const float4*>((const float*)xb + xoff + base);
        v[0] = r.x; v[1] = r.y; v[2] = r.z; v[3] = r.w;
    }
    u16 o[4];
#pragma unroll
    for (int j = 0; j < 4; ++j)
        o[j] = f2b(ldext(w, c0 + j, isbf) * asinhf(v[j]) + ldext(b, c0 + j, isbf));
    *reinterpret_cast<uint2*>(y + base) = *reinterpret_cast<uint2*>(o);
}

// =====================================================================
// Weight-stationary streaming GEMM. C[M][N] = A[M][K] @ BT[N][K]^T + bias.
// Block: stages B-chunk [NCH][K] into LDS ONCE (frag-major layout, 64 KB),
// then streams M-rows with ZERO barriers in the main loop.
// mfma_32x32x16_bf16; wave-tile 32 rows x NCH cols; block = 4 waves = 128 rows/iter.
// LDS frag-major: frag f=(ks*NF+nf) holds BT[n0+nf*32+(l&31)][ks*16+(l>>5)*8 ..+8)
//   at lB[f*1024B + lane*16B] -> lane-linear ds_read (conflict-free, base+imm).
// C layout (HW-verified): col = lane&31 (n), row = (r&3)+8*(r>>2)+4*(lane>>5) (m).
// Store instr covers 64B contiguous per row -> no write amplification.
// EPI 0: bf16   1: GELU->bf16   2: +res ext -> ext   4: +res bf16 -> ext
// EPI 5: +res ext -> bf16 AND side-write n2w*asinh(v)+n2b -> out2 (bf16)
// =====================================================================
template <int K, int NCH, int EPI>
__global__ __launch_bounds__(256, 2) void sgemm2(
    const u16* __restrict__ A, const u16* __restrict__ BT, const void* __restrict__ bias,
    const void* __restrict__ resb, size_t resoff, void* __restrict__ outb, size_t outoff,
    int N, int Mtot, const int* __restrict__ flag,
    const void* __restrict__ n2w, const void* __restrict__ n2b, u16* __restrict__ out2) {
    constexpr int NF = NCH / 32;     // n-frags per wave
    constexpr int KS = K / 16;       // k-steps
    constexpr int FRAGS = KS * NF;   // 64 for both (256,128) and (512,64)
    __shared__ __align__(16) u16 lB[FRAGS * 512];   // 64 KB
    const int isbf = *flag;
    const int tid = threadIdx.x;
    const int lane = tid & 63, wave = tid >> 6;
    const int n0 = blockIdx.x * NCH;

    // ---- stage B once (reg -> LDS, frag-major) ----
    for (int f = wave; f < FRAGS; f += 4) {
        int nf = f % NF, ks = f / NF;
        const u16* src = BT + (size_t)(n0 + nf * 32 + (lane & 31)) * K + ks * 16 + (lane >> 5) * 8;
        *reinterpret_cast<short8*>(&lB[f * 512 + lane * 8]) =
            *reinterpret_cast<const short8*>(src);
    }

    // per-lane column constants (loop-invariant)
    float bias_r[NF], w2r[NF], b2r[NF];
#pragma unroll
    for (int nf = 0; nf < NF; ++nf) {
        int colg = n0 + nf * 32 + (lane & 31);
        bias_r[nf] = ldext(bias, colg, isbf);
        if (EPI == 5) {
            w2r[nf] = ldext(n2w, colg, isbf);
            b2r[nf] = ldext(n2b, colg, isbf);
        }
    }
    __syncthreads();   // B resident; no barriers after this

    const int rows_per_blk = Mtot / (int)gridDim.y;
    const int row_base = blockIdx.y * rows_per_blk;
    const int arow = wave * 32 + (lane & 31);
    const int acol = (lane >> 5) * 8;

    for (int r0 = row_base; r0 < row_base + rows_per_blk; r0 += 128) {
        const u16* ap = A + (size_t)(r0 + arow) * K + acol;
        short8 a[KS];
#pragma unroll
        for (int ks = 0; ks < KS; ++ks)
            a[ks] = *reinterpret_cast<const short8*>(ap + ks * 16);

        f32x16 acc[NF];
#pragma unroll
        for (int nf = 0; nf < NF; ++nf)
#pragma unroll
            for (int i = 0; i < 16; ++i) acc[nf][i] = 0.f;

#pragma unroll
        for (int ks = 0; ks < KS; ++ks)
#pragma unroll
            for (int nf = 0; nf < NF; ++nf) {
                short8 b = *reinterpret_cast<const short8*>(&lB[(ks * NF + nf) * 512 + lane * 8]);
                acc[nf] = __builtin_amdgcn_mfma_f32_32x32x16_bf16(a[ks], b, acc[nf], 0, 0, 0);
            }

        // epilogue: one store instr = 2 rows x 64B contiguous
#pragma unroll
        for (int nf = 0; nf < NF; ++nf) {
            int colg = n0 + nf * 32 + (lane & 31);
#pragma unroll
            for (int rr = 0; rr < 16; ++rr) {
                int m = (rr & 3) + 8 * (rr >> 2) + 4 * (lane >> 5);
                int rowg = r0 + wave * 32 + m;
                size_t idx = (size_t)rowg * N + colg;
                float v = acc[nf][rr] + bias_r[nf];
                if (EPI == 0) {
                    ((u16*)outb)[outoff + idx] = f2b(v);
                } else if (EPI == 1) {
                    v = 0.5f * v * (1.f + erff(v * 0.70710678118654752f));
                    ((u16*)outb)[outoff + idx] = f2b(v);
                } else if (EPI == 2) {
                    v += ldext(resb, resoff + idx, isbf);
                    stext(outb, outoff + idx, isbf, v);
                } else if (EPI == 4) {
                    v += b2f(((const u16*)resb)[resoff + idx]);
                    stext(outb, outoff + idx, isbf, v);
                } else {  // EPI == 5
                    v += ldext(resb, resoff + idx, isbf);
                    ((u16*)outb)[outoff + idx] = f2b(v);
                    float y = w2r[nf] * asinhf(v) + b2r[nf];
                    out2[idx] = f2b(y);
                }
            }
        }
    }
}

// ---------- neighborhood attention: thread = (pixel, head), all in registers ----------
// qkv: [P][768] bf16 (q|k|v, each 256 = 8 heads x 32). out: [P][256] bf16.
__global__ __launch_bounds__(256) void attn_k(const u16* __restrict__ qkv, u16* __restrict__ out) {
    const int t = blockIdx.x * 256 + threadIdx.x;
    const int head = t & 7;
    const int p = t >> 3;
    const int b = p >> 12;
    const int ij = p & 4095;
    const int i = ij >> 6, j = ij & 63;
    int r0 = i - 1; r0 = r0 < 0 ? 0 : (r0 > 61 ? 61 : r0);
    int c0 = j - 1; c0 = c0 < 0 ? 0 : (c0 > 61 ? 61 : c0);

    const u16* qp = qkv + (size_t)p * 768 + head * 32;
    float q[32];
#pragma unroll
    for (int ch = 0; ch < 4; ++ch)
        unpack8(*reinterpret_cast<const uint4*>(qp + ch * 8), q + ch * 8);

    const float qscale = 0.17677669529663687f;  // 32^-0.5
    int nbp[9];
    float sc[9];
#pragma unroll
    for (int dr = 0; dr < 3; ++dr)
#pragma unroll
        for (int dc = 0; dc < 3; ++dc) {
            int nb = dr * 3 + dc;
            int np_ = b * 4096 + (r0 + dr) * 64 + (c0 + dc);
            nbp[nb] = np_;
            const u16* kp = qkv + (size_t)np_ * 768 + 256 + head * 32;
            float dot = 0.f;
#pragma unroll
            for (int ch = 0; ch < 4; ++ch) {
                float kf[8];
                unpack8(*reinterpret_cast<const uint4*>(kp + ch * 8), kf);
#pragma unroll
                for (int e = 0; e < 8; ++e) dot += q[ch * 8 + e] * kf[e];
            }
            sc[nb] = dot * qscale;
        }

    float mx = sc[0];
#pragma unroll
    for (int nb = 1; nb < 9; ++nb) mx = fmaxf(mx, sc[nb]);
    float s = 0.f;
#pragma unroll
    for (int nb = 0; nb < 9; ++nb) { sc[nb] = __expf(sc[nb] - mx); s += sc[nb]; }
    float inv = 1.f / s;

    float acc[32];
#pragma unroll
    for (int e = 0; e < 32; ++e) acc[e] = 0.f;
#pragma unroll
    for (int nb = 0; nb < 9; ++nb) {
        const u16* vp = qkv + (size_t)nbp[nb] * 768 + 512 + head * 32;
        float wgt = sc[nb] * inv;
#pragma unroll
        for (int ch = 0; ch < 4; ++ch) {
            float vf[8];
            unpack8(*reinterpret_cast<const uint4*>(vp + ch * 8), vf);
#pragma unroll
            for (int e = 0; e < 8; ++e) acc[ch * 8 + e] += wgt * vf[e];
        }
    }

    u16 ob[32];
#pragma unroll
    for (int e = 0; e < 32; ++e) ob[e] = f2b(acc[e]);
    uint4* ov = reinterpret_cast<uint4*>(ob);
    uint4* og = reinterpret_cast<uint4*>(out + (size_t)p * 256 + head * 32);
#pragma unroll
    for (int ch = 0; ch < 4; ++ch) og[ch] = ov[ch];
}

extern "C" void kernel_launch(void* const* d_in, const int* in_sizes, int n_in,
                              void* d_out, int out_size, void* d_ws, size_t ws_size,
                              hipStream_t stream) {
    const void* h      = d_in[0];
    const void* qkv_w  = d_in[1];
    const void* qkv_b  = d_in[2];
    const void* proj_w = d_in[3];
    const void* proj_b = d_in[4];
    const void* n1_w   = d_in[5];
    const void* n1_b   = d_in[6];
    const void* n2_w   = d_in[7];
    const void* n2_b   = d_in[8];
    const void* w1     = d_in[9];
    const void* b1     = d_in[10];
    const void* w2     = d_in[11];
    const void* b2     = d_in[12];

    char* ws = (char*)d_ws;
    u16* WqkvT  = (u16*)(ws + 0);          // [768][256]
    u16* WprojT = (u16*)(ws + 393216);     // [256][256]
    u16* W1T    = (u16*)(ws + 524288);     // [512][256]
    u16* W2T    = (u16*)(ws + 786432);     // [256][512]
    int* Flag   = (int*)(ws + 1048576);
    char* bufs  = ws + 1049600;

    size_t avail = ws_size > 1049600 ? ws_size - 1049600 : 0;
    int CHUNK = 4096;
    if (avail >= (size_t)65536 * 2048) CHUNK = 65536;
    else if (avail >= (size_t)16384 * 2048) CHUNK = 16384;
    else if (avail >= (size_t)8192 * 2048) CHUNK = 8192;

    u16* H1 = (u16*)bufs;                          // [CHUNK][256] bf16
    u16* S  = (u16*)(bufs + (size_t)CHUNK * 512);  // [CHUNK][768] bf16

    detect_k<<<1, 256, 0, stream>>>(h, Flag);
    transpose_k<<<768, 256, 0, stream>>>(qkv_w, WqkvT, 256, 768, Flag);
    transpose_k<<<256, 256, 0, stream>>>(proj_w, WprojT, 256, 256, Flag);
    transpose_k<<<512, 256, 0, stream>>>(w1, W1T, 256, 512, Flag);
    transpose_k<<<512, 256, 0, stream>>>(w2, W2T, 512, 256, Flag);

    if (CHUNK == 65536) {
        u16* HNS = S;                               // [65536][256] bf16 (qkv dead after attn)
        u16* T   = S + (size_t)65536 * 256;         // [65536][512] bf16
        u16* N2  = (u16*)d_out;                     // scratch: normed hnew, consumed by MLP1
                                                    // before MLP2 overwrites d_out (stream-ordered)
        norm_k<<<16384, 256, 0, stream>>>(h, 0, n1_w, n1_b, H1, Flag, 0);
        // qkv = H1 @ WqkvT + b
        { dim3 g(6, 128); sgemm2<256, 128, 0><<<g, 256, 0, stream>>>(
              H1, WqkvT, qkv_b, nullptr, 0, S, 0, 768, 65536, Flag, nullptr, nullptr, nullptr); }
        attn_k<<<2048, 256, 0, stream>>>(S, H1);
        // hnew = h + attn @ WprojT + b -> HNS bf16; side: N2 = n2 o hnew
        { dim3 g(2, 256); sgemm2<256, 128, 5><<<g, 256, 0, stream>>>(
              H1, WprojT, proj_b, h, 0, HNS, 0, 256, 65536, Flag, n2_w, n2_b, N2); }
        // T = gelu(N2 @ W1T + b1)
        { dim3 g(4, 128); sgemm2<256, 128, 1><<<g, 256, 0, stream>>>(
              N2, W1T, b1, nullptr, 0, T, 0, 512, 65536, Flag, nullptr, nullptr, nullptr); }
        // out = HNS + T @ W2T + b2
        { dim3 g(4, 128); sgemm2<512, 64, 4><<<g, 256, 0, stream>>>(
              T, W2T, b2, HNS, 0, d_out, 0, 256, 65536, Flag, nullptr, nullptr, nullptr); }
    } else {
        const int NCH = 65536 / CHUNK;
        for (int c = 0; c < NCH; ++c) {
            size_t off = (size_t)c * CHUNK * 256;
            norm_k<<<CHUNK / 4, 256, 0, stream>>>(h, off, n1_w, n1_b, H1, Flag, 0);
            { dim3 g(6, CHUNK / 128); sgemm2<256, 128, 0><<<g, 256, 0, stream>>>(
                  H1, WqkvT, qkv_b, nullptr, 0, S, 0, 768, CHUNK, Flag, nullptr, nullptr, nullptr); }
            attn_k<<<CHUNK / 32, 256, 0, stream>>>(S, H1);
            { dim3 g(2, CHUNK / 128); sgemm2<256, 128, 2><<<g, 256, 0, stream>>>(
                  H1, WprojT, proj_b, h, off, d_out, off, 256, CHUNK, Flag, nullptr, nullptr, nullptr); }
        }
        for (int c = 0; c < NCH; ++c) {
            size_t off = (size_t)c * CHUNK * 256;
            norm_k<<<CHUNK / 4, 256, 0, stream>>>(d_out, off, n2_w, n2_b, H1, Flag, 0);
            { dim3 g(4, CHUNK / 128); sgemm2<256, 128, 1><<<g, 256, 0, stream>>>(
                  H1, W1T, b1, nullptr, 0, S, 0, 512, CHUNK, Flag, nullptr, nullptr, nullptr); }
            { dim3 g(4, CHUNK / 128); sgemm2<512, 64, 2><<<g, 256, 0, stream>>>(
                  S, W2T, b2, d_out, off, d_out, off, 256, CHUNK, Flag, nullptr, nullptr, nullptr); }
        }
    }
}

// Round 6
// 495.979 us; speedup vs baseline: 1.4699x; 1.4699x over previous
//
#include <hip/hip_runtime.h>
#include <math.h>

typedef unsigned short u16;
typedef unsigned int u32;
typedef __attribute__((ext_vector_type(8))) short short8;
typedef __attribute__((ext_vector_type(4))) float f32x4;

__device__ __forceinline__ float b2f(u16 u) {
    return __uint_as_float(((u32)u) << 16);
}
__device__ __forceinline__ u16 f2b(float f) {
    u32 x = __float_as_uint(f);
    return (u16)((x + 0x7fffu + ((x >> 16) & 1u)) >> 16);   // RNE
}
__device__ __forceinline__ float ldext(const void* p, size_t i, int isbf) {
    return isbf ? b2f(((const u16*)p)[i]) : ((const float*)p)[i];
}
__device__ __forceinline__ void stext(void* p, size_t i, int isbf, float v) {
    if (isbf) ((u16*)p)[i] = f2b(v);
    else ((float*)p)[i] = v;
}
// async global->LDS, 16B per lane; lds base must be wave-uniform (HW adds lane*16)
__device__ __forceinline__ void gl2lds16(const u16* g, u16* l) {
    __builtin_amdgcn_global_load_lds(
        (const __attribute__((address_space(1))) u32*)(const void*)g,
        (__attribute__((address_space(3))) u32*)(void*)l, 16, 0, 0);
}
// unpack 8 bf16 (uint4) -> 8 f32
__device__ __forceinline__ void unpack8(uint4 w, float* f) {
    const u32* pw = (const u32*)&w;
#pragma unroll
    for (int k = 0; k < 4; ++k) {
        f[2 * k]     = __uint_as_float(pw[k] << 16);
        f[2 * k + 1] = __uint_as_float(pw[k] & 0xffff0000u);
    }
}

// ---------- dtype detector: 1 if h is bf16, 0 if f32 ----------
__global__ void detect_k(const void* __restrict__ h, int* __restrict__ flag) {
    __shared__ int cnt;
    if (threadIdx.x == 0) cnt = 0;
    __syncthreads();
    const u16* p = (const u16*)h;
    int local = 0;
    for (int i = threadIdx.x; i < 4096; i += 256) {
        int e = (p[i] >> 7) & 0xFF;
        if (e != 0 && (e < 110 || e > 133)) local++;
    }
    atomicAdd(&cnt, local);
    __syncthreads();
    if (threadIdx.x == 0) *flag = (cnt < 256) ? 1 : 0;
}

// ---------- transpose ext weight -> bf16 [C][R] ----------
__global__ void transpose_k(const void* __restrict__ src, u16* __restrict__ dst,
                            int R, int C, const int* __restrict__ flag) {
    int isbf = *flag;
    int idx = blockIdx.x * 256 + threadIdx.x;
    if (idx >= R * C) return;
    int r = idx / C, c = idx - r * C;
    dst[c * R + r] = f2b(ldext(src, idx, isbf));
}

// ---------- arsinh norm: y = w[c]*asinh(x)+b[c]; in: ext or forced-bf16; out bf16 ----------
__global__ void norm_k(const void* __restrict__ xb, size_t xoff,
                       const void* __restrict__ w, const void* __restrict__ b,
                       u16* __restrict__ y, const int* __restrict__ flag, int force_bf) {
    int isbf = *flag;
    int xisbf = force_bf ? 1 : isbf;
    size_t base = ((size_t)blockIdx.x * 256 + threadIdx.x) * 4;
    int c0 = (int)(base & 255);
    float v[4];
    if (xisbf) {
        uint2 raw = *reinterpret_cast<const uint2*>((const u16*)xb + xoff + base);
        const u16* px = reinterpret_cast<const u16*>(&raw);
#pragma unroll
        for (int j = 0; j < 4; ++j) v[j] = b2f(px[j]);
    } else {
        float4 r = *reinterpret_cast<const float4*>((const float*)xb + xoff + base);
        v[0] = r.x; v[1] = r.y; v[2] = r.z; v[3] = r.w;
    }
    u16 o[4];
#pragma unroll
    for (int j = 0; j < 4; ++j)
        o[j] = f2b(ldext(w, c0 + j, isbf) * asinhf(v[j]) + ldext(b, c0 + j, isbf));
    *reinterpret_cast<uint2*>(y + base) = *reinterpret_cast<uint2*>(o);
}

// ---------- GEMM: C[M][N] = A[M][K] @ BT[N][K]^T + bias(ext), bf16 MFMA ----------
// Round-0 structure (128x128 tile, BK=32, gl2lds) + two fixes:
//  * 2-phase double-buffered LDS: STAGE(t+1) issued BEFORE compute(t); ONE
//    __syncthreads per K-step (was 2). Loads progress under MFMA.
//  * XCD swizzle: same-A x-siblings made consecutive on the same XCD (L2 share).
// EPI 0: store bf16            1: GELU, store bf16
// EPI 2: +res ext, store ext   3: +res ext, store bf16   4: +res bf16, store ext
// EPI 5: +res ext, store bf16 AND side-write n2w*asinh(v)+n2b -> out2 (bf16)
template <int EPI>
__global__ __launch_bounds__(256) void gemm_bt(
    const u16* __restrict__ A, const u16* __restrict__ BT, const void* __restrict__ bias,
    const void* __restrict__ resb, size_t resoff, void* __restrict__ outb, size_t outoff,
    int N, int K, const int* __restrict__ flag,
    const void* __restrict__ n2w, const void* __restrict__ n2b, u16* __restrict__ out2) {
    __shared__ __align__(16) u16 lA[2][128 * 32];   // 2 x 8 KB
    __shared__ __align__(16) u16 lB[2][128 * 32];   // 2 x 8 KB
    const int isbf = *flag;
    const int tid = threadIdx.x;
    const int lane = tid & 63;
    const int wave = tid >> 6;
    const int waveM = wave >> 1, waveN = wave & 1;

    // XCD swizzle: hw flat id -> logical tile; groups gridDim.x A-sharing
    // siblings consecutively on one XCD (flat%8 ~ XCD; bijective when nblk%8==0)
    const int gx = gridDim.x;
    int nblk = gx * gridDim.y;
    int bflat = blockIdx.y * gx + blockIdx.x;
    int L = bflat;
    if ((nblk & 7) == 0) {
        int per = nblk >> 3;
        L = (bflat & 7) * per + (bflat >> 3);
    }
    const int m0 = (L / gx) * 128;
    const int n0 = (L % gx) * 128;

    f32x4 acc[4][4];
#pragma unroll
    for (int mi = 0; mi < 4; ++mi)
#pragma unroll
        for (int ni = 0; ni < 4; ++ni)
#pragma unroll
            for (int r = 0; r < 4; ++r) acc[mi][ni][r] = 0.f;

    const int lrow = lane & 15;
    const int ko = (lane >> 4) * 8;
    // staging geometry (wave-uniform LDS bases, per-lane global srcs)
    const int s0 = wave * 2, s1 = wave * 2 + 1;
    const int e0a = (s0 * 64 + lane) * 8, e1a = (s1 * 64 + lane) * 8;
    const int row0 = e0a >> 5, col0 = e0a & 31;
    const int row1 = e1a >> 5, col1 = e1a & 31;

    const int NT = K >> 5;
    // prologue: stage tile 0 into buffer 0
    gl2lds16(&A[(size_t)(m0 + row0) * K + col0], &lA[0][s0 * 512]);
    gl2lds16(&BT[(size_t)(n0 + row0) * K + col0], &lB[0][s0 * 512]);
    gl2lds16(&A[(size_t)(m0 + row1) * K + col1], &lA[0][s1 * 512]);
    gl2lds16(&BT[(size_t)(n0 + row1) * K + col1], &lB[0][s1 * 512]);
    __syncthreads();

    int cur = 0;
    for (int t = 0; t < NT; ++t) {
        if (t + 1 < NT) {   // prefetch next K-tile into the other buffer
            int k0 = (t + 1) << 5;
            gl2lds16(&A[(size_t)(m0 + row0) * K + k0 + col0], &lA[cur ^ 1][s0 * 512]);
            gl2lds16(&BT[(size_t)(n0 + row0) * K + k0 + col0], &lB[cur ^ 1][s0 * 512]);
            gl2lds16(&A[(size_t)(m0 + row1) * K + k0 + col1], &lA[cur ^ 1][s1 * 512]);
            gl2lds16(&BT[(size_t)(n0 + row1) * K + k0 + col1], &lB[cur ^ 1][s1 * 512]);
        }
        short8 af[4], bfr[4];
#pragma unroll
        for (int mi = 0; mi < 4; ++mi)
            af[mi] = *reinterpret_cast<const short8*>(&lA[cur][(waveM * 64 + mi * 16 + lrow) * 32 + ko]);
#pragma unroll
        for (int ni = 0; ni < 4; ++ni)
            bfr[ni] = *reinterpret_cast<const short8*>(&lB[cur][(waveN * 64 + ni * 16 + lrow) * 32 + ko]);
#pragma unroll
        for (int mi = 0; mi < 4; ++mi)
#pragma unroll
            for (int ni = 0; ni < 4; ++ni)
                acc[mi][ni] = __builtin_amdgcn_mfma_f32_16x16x32_bf16(af[mi], bfr[ni], acc[mi][ni], 0, 0, 0);
        __syncthreads();   // drains prefetch (vmcnt0) + all waves done reading cur
        cur ^= 1;
    }

    const int rquad = (lane >> 4) * 4;
    const int ccol = lane & 15;
#pragma unroll
    for (int mi = 0; mi < 4; ++mi)
#pragma unroll
        for (int ni = 0; ni < 4; ++ni) {
            int colg = n0 + waveN * 64 + ni * 16 + ccol;
            float bb = ldext(bias, colg, isbf);
#pragma unroll
            for (int r = 0; r < 4; ++r) {
                int rowg = m0 + waveM * 64 + mi * 16 + rquad + r;
                size_t idx = (size_t)rowg * N + colg;
                float v = acc[mi][ni][r] + bb;
                if (EPI == 0) {
                    ((u16*)outb)[outoff + idx] = f2b(v);
                } else if (EPI == 1) {
                    v = 0.5f * v * (1.f + erff(v * 0.70710678118654752f));
                    ((u16*)outb)[outoff + idx] = f2b(v);
                } else if (EPI == 2) {
                    v += ldext(resb, resoff + idx, isbf);
                    stext(outb, outoff + idx, isbf, v);
                } else if (EPI == 3) {
                    v += ldext(resb, resoff + idx, isbf);
                    ((u16*)outb)[outoff + idx] = f2b(v);
                } else if (EPI == 4) {
                    v += b2f(((const u16*)resb)[resoff + idx]);
                    stext(outb, outoff + idx, isbf, v);
                } else {  // EPI == 5: hnew = v + res; write bf16(hnew) and norm2(hnew)
                    v += ldext(resb, resoff + idx, isbf);
                    ((u16*)outb)[outoff + idx] = f2b(v);
                    float y = ldext(n2w, colg, isbf) * asinhf(v) + ldext(n2b, colg, isbf);
                    out2[idx] = f2b(y);
                }
            }
        }
}

// ---------- neighborhood attention: thread = (pixel, head), all in registers ----------
// qkv: [P][768] bf16 (q|k|v, each 256 = 8 heads x 32). out: [P][256] bf16.
__global__ __launch_bounds__(256) void attn_k(const u16* __restrict__ qkv, u16* __restrict__ out) {
    const int t = blockIdx.x * 256 + threadIdx.x;
    const int head = t & 7;
    const int p = t >> 3;
    const int b = p >> 12;
    const int ij = p & 4095;
    const int i = ij >> 6, j = ij & 63;
    int r0 = i - 1; r0 = r0 < 0 ? 0 : (r0 > 61 ? 61 : r0);
    int c0 = j - 1; c0 = c0 < 0 ? 0 : (c0 > 61 ? 61 : c0);

    const u16* qp = qkv + (size_t)p * 768 + head * 32;
    float q[32];
#pragma unroll
    for (int ch = 0; ch < 4; ++ch)
        unpack8(*reinterpret_cast<const uint4*>(qp + ch * 8), q + ch * 8);

    const float qscale = 0.17677669529663687f;  // 32^-0.5
    int nbp[9];
    float sc[9];
#pragma unroll
    for (int dr = 0; dr < 3; ++dr)
#pragma unroll
        for (int dc = 0; dc < 3; ++dc) {
            int nb = dr * 3 + dc;
            int np_ = b * 4096 + (r0 + dr) * 64 + (c0 + dc);
            nbp[nb] = np_;
            const u16* kp = qkv + (size_t)np_ * 768 + 256 + head * 32;
            float dot = 0.f;
#pragma unroll
            for (int ch = 0; ch < 4; ++ch) {
                float kf[8];
                unpack8(*reinterpret_cast<const uint4*>(kp + ch * 8), kf);
#pragma unroll
                for (int e = 0; e < 8; ++e) dot += q[ch * 8 + e] * kf[e];
            }
            sc[nb] = dot * qscale;
        }

    float mx = sc[0];
#pragma unroll
    for (int nb = 1; nb < 9; ++nb) mx = fmaxf(mx, sc[nb]);
    float s = 0.f;
#pragma unroll
    for (int nb = 0; nb < 9; ++nb) { sc[nb] = __expf(sc[nb] - mx); s += sc[nb]; }
    float inv = 1.f / s;

    float acc[32];
#pragma unroll
    for (int e = 0; e < 32; ++e) acc[e] = 0.f;
#pragma unroll
    for (int nb = 0; nb < 9; ++nb) {
        const u16* vp = qkv + (size_t)nbp[nb] * 768 + 512 + head * 32;
        float wgt = sc[nb] * inv;
#pragma unroll
        for (int ch = 0; ch < 4; ++ch) {
            float vf[8];
            unpack8(*reinterpret_cast<const uint4*>(vp + ch * 8), vf);
#pragma unroll
            for (int e = 0; e < 8; ++e) acc[ch * 8 + e] += wgt * vf[e];
        }
    }

    u16 ob[32];
#pragma unroll
    for (int e = 0; e < 32; ++e) ob[e] = f2b(acc[e]);
    uint4* ov = reinterpret_cast<uint4*>(ob);
    uint4* og = reinterpret_cast<uint4*>(out + (size_t)p * 256 + head * 32);
#pragma unroll
    for (int ch = 0; ch < 4; ++ch) og[ch] = ov[ch];
}

extern "C" void kernel_launch(void* const* d_in, const int* in_sizes, int n_in,
                              void* d_out, int out_size, void* d_ws, size_t ws_size,
                              hipStream_t stream) {
    const void* h      = d_in[0];
    const void* qkv_w  = d_in[1];
    const void* qkv_b  = d_in[2];
    const void* proj_w = d_in[3];
    const void* proj_b = d_in[4];
    const void* n1_w   = d_in[5];
    const void* n1_b   = d_in[6];
    const void* n2_w   = d_in[7];
    const void* n2_b   = d_in[8];
    const void* w1     = d_in[9];
    const void* b1     = d_in[10];
    const void* w2     = d_in[11];
    const void* b2     = d_in[12];

    char* ws = (char*)d_ws;
    u16* WqkvT  = (u16*)(ws + 0);          // [768][256]
    u16* WprojT = (u16*)(ws + 393216);     // [256][256]
    u16* W1T    = (u16*)(ws + 524288);     // [512][256]
    u16* W2T    = (u16*)(ws + 786432);     // [256][512]
    int* Flag   = (int*)(ws + 1048576);
    char* bufs  = ws + 1049600;

    size_t avail = ws_size > 1049600 ? ws_size - 1049600 : 0;
    int CHUNK = 4096;
    if (avail >= (size_t)65536 * 2048) CHUNK = 65536;
    else if (avail >= (size_t)16384 * 2048) CHUNK = 16384;
    else if (avail >= (size_t)8192 * 2048) CHUNK = 8192;

    u16* H1 = (u16*)bufs;                          // [CHUNK][256] bf16
    u16* S  = (u16*)(bufs + (size_t)CHUNK * 512);  // [CHUNK][768] bf16

    detect_k<<<1, 256, 0, stream>>>(h, Flag);
    transpose_k<<<768, 256, 0, stream>>>(qkv_w, WqkvT, 256, 768, Flag);
    transpose_k<<<256, 256, 0, stream>>>(proj_w, WprojT, 256, 256, Flag);
    transpose_k<<<512, 256, 0, stream>>>(w1, W1T, 256, 512, Flag);
    transpose_k<<<512, 256, 0, stream>>>(w2, W2T, 512, 256, Flag);

    if (CHUNK == 65536) {
        u16* HNS = S;                               // [65536][256] bf16 (qkv dead after attn)
        u16* T   = S + (size_t)65536 * 256;         // [65536][512] bf16
        u16* N2  = (u16*)d_out;                     // scratch: normed hnew, consumed by MLP1
                                                    // before MLP2 overwrites d_out (stream-ordered)
        norm_k<<<16384, 256, 0, stream>>>(h, 0, n1_w, n1_b, H1, Flag, 0);
        // qkv = H1 @ WqkvT + b
        { dim3 g(6, 512); gemm_bt<0><<<g, 256, 0, stream>>>(H1, WqkvT, qkv_b, nullptr, 0, S, 0,
                                                            768, 256, Flag, nullptr, nullptr, nullptr); }
        attn_k<<<2048, 256, 0, stream>>>(S, H1);
        // hnew = h + attn @ WprojT + b -> HNS bf16; side: N2 = n2 o hnew
        { dim3 g(2, 512); gemm_bt<5><<<g, 256, 0, stream>>>(H1, WprojT, proj_b, h, 0, HNS, 0,
                                                            256, 256, Flag, n2_w, n2_b, N2); }
        // T = gelu(N2 @ W1T + b1)
        { dim3 g(4, 512); gemm_bt<1><<<g, 256, 0, stream>>>(N2, W1T, b1, nullptr, 0, T, 0,
                                                            512, 256, Flag, nullptr, nullptr, nullptr); }
        // out = HNS + T @ W2T + b2
        { dim3 g(2, 512); gemm_bt<4><<<g, 256, 0, stream>>>(T, W2T, b2, HNS, 0, d_out, 0,
                                                            256, 512, Flag, nullptr, nullptr, nullptr); }
    } else {
        const int NCH = 65536 / CHUNK;
        for (int c = 0; c < NCH; ++c) {
            size_t off = (size_t)c * CHUNK * 256;
            norm_k<<<CHUNK / 4, 256, 0, stream>>>(h, off, n1_w, n1_b, H1, Flag, 0);
            { dim3 g(6, CHUNK / 128);
              gemm_bt<0><<<g, 256, 0, stream>>>(H1, WqkvT, qkv_b, nullptr, 0, S, 0,
                                                768, 256, Flag, nullptr, nullptr, nullptr); }
            attn_k<<<CHUNK / 32, 256, 0, stream>>>(S, H1);
            { dim3 g(2, CHUNK / 128);
              gemm_bt<2><<<g, 256, 0, stream>>>(H1, WprojT, proj_b, h, off, d_out, off,
                                                256, 256, Flag, nullptr, nullptr, nullptr); }
        }
        for (int c = 0; c < NCH; ++c) {
            size_t off = (size_t)c * CHUNK * 256;
            norm_k<<<CHUNK / 4, 256, 0, stream>>>(d_out, off, n2_w, n2_b, H1, Flag, 0);
            { dim3 g(4, CHUNK / 128);
              gemm_bt<1><<<g, 256, 0, stream>>>(H1, W1T, b1, nullptr, 0, S, 0,
                                                512, 256, Flag, nullptr, nullptr, nullptr); }
            { dim3 g(2, CHUNK / 128);
              gemm_bt<2><<<g, 256, 0, stream>>>(S, W2T, b2, d_out, off, d_out, off,
                                                256, 512, Flag, nullptr, nullptr, nullptr); }
        }
    }
}

// Round 7
// 448.530 us; speedup vs baseline: 1.6254x; 1.1058x over previous
//
#include <hip/hip_runtime.h>
#include <math.h>

typedef unsigned short u16;
typedef unsigned int u32;
typedef __attribute__((ext_vector_type(8))) short short8;
typedef __attribute__((ext_vector_type(4))) float f32x4;

__device__ __forceinline__ float b2f(u16 u) {
    return __uint_as_float(((u32)u) << 16);
}
__device__ __forceinline__ u16 f2b(float f) {
    u32 x = __float_as_uint(f);
    return (u16)((x + 0x7fffu + ((x >> 16) & 1u)) >> 16);   // RNE
}
__device__ __forceinline__ float ldext(const void* p, size_t i, int isbf) {
    return isbf ? b2f(((const u16*)p)[i]) : ((const float*)p)[i];
}
__device__ __forceinline__ void stext(void* p, size_t i, int isbf, float v) {
    if (isbf) ((u16*)p)[i] = f2b(v);
    else ((float*)p)[i] = v;
}
// branch-free asinh: copysign(ln(|x|+sqrt(x^2+1)), x). v_sqrt+v_log, ~6 ops.
__device__ __forceinline__ float fast_asinh(float x) {
    float ax = fabsf(x);
    float s = sqrtf(fmaf(ax, ax, 1.f));
    float l = __logf(ax + s);
    return copysignf(l, x);
}
// tanh-form GELU: x*t/(t+1), t=exp(2*0.79788456*(x+0.044715x^3)). 1 exp + 1 rcp.
__device__ __forceinline__ float fast_gelu(float x) {
    float x2 = x * x;
    float inner = fmaf(0.044715f * x2, x, x);
    float t = __expf(1.5957691216057308f * inner);
    return x * t * __builtin_amdgcn_rcpf(t + 1.f);
}
// async global->LDS, 16B per lane; lds base must be wave-uniform (HW adds lane*16)
__device__ __forceinline__ void gl2lds16(const u16* g, u16* l) {
    __builtin_amdgcn_global_load_lds(
        (const __attribute__((address_space(1))) u32*)(const void*)g,
        (__attribute__((address_space(3))) u32*)(void*)l, 16, 0, 0);
}
// unpack 8 bf16 (uint4) -> 8 f32
__device__ __forceinline__ void unpack8(uint4 w, float* f) {
    const u32* pw = (const u32*)&w;
#pragma unroll
    for (int k = 0; k < 4; ++k) {
        f[2 * k]     = __uint_as_float(pw[k] << 16);
        f[2 * k + 1] = __uint_as_float(pw[k] & 0xffff0000u);
    }
}

// ---------- dtype detector: 1 if h is bf16, 0 if f32 ----------
__global__ void detect_k(const void* __restrict__ h, int* __restrict__ flag) {
    __shared__ int cnt;
    if (threadIdx.x == 0) cnt = 0;
    __syncthreads();
    const u16* p = (const u16*)h;
    int local = 0;
    for (int i = threadIdx.x; i < 4096; i += 256) {
        int e = (p[i] >> 7) & 0xFF;
        if (e != 0 && (e < 110 || e > 133)) local++;
    }
    atomicAdd(&cnt, local);
    __syncthreads();
    if (threadIdx.x == 0) *flag = (cnt < 256) ? 1 : 0;
}

// ---------- transpose ext weight -> bf16 [C][R] ----------
__global__ void transpose_k(const void* __restrict__ src, u16* __restrict__ dst,
                            int R, int C, const int* __restrict__ flag) {
    int isbf = *flag;
    int idx = blockIdx.x * 256 + threadIdx.x;
    if (idx >= R * C) return;
    int r = idx / C, c = idx - r * C;
    dst[c * R + r] = f2b(ldext(src, idx, isbf));
}

// ---------- arsinh norm: y = w[c]*asinh(x)+b[c]; in: ext or forced-bf16; out bf16 ----------
__global__ void norm_k(const void* __restrict__ xb, size_t xoff,
                       const void* __restrict__ w, const void* __restrict__ b,
                       u16* __restrict__ y, const int* __restrict__ flag, int force_bf) {
    int isbf = *flag;
    int xisbf = force_bf ? 1 : isbf;
    size_t base = ((size_t)blockIdx.x * 256 + threadIdx.x) * 4;
    int c0 = (int)(base & 255);
    float v[4];
    if (xisbf) {
        uint2 raw = *reinterpret_cast<const uint2*>((const u16*)xb + xoff + base);
        const u16* px = reinterpret_cast<const u16*>(&raw);
#pragma unroll
        for (int j = 0; j < 4; ++j) v[j] = b2f(px[j]);
    } else {
        float4 r = *reinterpret_cast<const float4*>((const float*)xb + xoff + base);
        v[0] = r.x; v[1] = r.y; v[2] = r.z; v[3] = r.w;
    }
    u16 o[4];
#pragma unroll
    for (int j = 0; j < 4; ++j)
        o[j] = f2b(ldext(w, c0 + j, isbf) * fast_asinh(v[j]) + ldext(b, c0 + j, isbf));
    *reinterpret_cast<uint2*>(y + base) = *reinterpret_cast<uint2*>(o);
}

// ---------- GEMM: C[M][N] = A[M][K] @ BT[N][K]^T + bias(ext), bf16 MFMA ----------
// Round-6 structure (128x128 tile, BK=32, gl2lds, 2-phase dbuf, XCD swizzle).
// Round-7: transcendental epilogues use fast_gelu / fast_asinh (branch-free,
// HW v_exp/v_log/v_sqrt) instead of libm erff/asinhf (~40-op branchy).
// EPI 0: store bf16            1: GELU, store bf16
// EPI 2: +res ext, store ext   3: +res ext, store bf16   4: +res bf16, store ext
// EPI 5: +res ext, store bf16 AND side-write n2w*asinh(v)+n2b -> out2 (bf16)
template <int EPI>
__global__ __launch_bounds__(256) void gemm_bt(
    const u16* __restrict__ A, const u16* __restrict__ BT, const void* __restrict__ bias,
    const void* __restrict__ resb, size_t resoff, void* __restrict__ outb, size_t outoff,
    int N, int K, const int* __restrict__ flag,
    const void* __restrict__ n2w, const void* __restrict__ n2b, u16* __restrict__ out2) {
    __shared__ __align__(16) u16 lA[2][128 * 32];   // 2 x 8 KB
    __shared__ __align__(16) u16 lB[2][128 * 32];   // 2 x 8 KB
    const int isbf = *flag;
    const int tid = threadIdx.x;
    const int lane = tid & 63;
    const int wave = tid >> 6;
    const int waveM = wave >> 1, waveN = wave & 1;

    // XCD swizzle: hw flat id -> logical tile; groups gridDim.x A-sharing
    // siblings consecutively on one XCD (flat%8 ~ XCD; bijective when nblk%8==0)
    const int gx = gridDim.x;
    int nblk = gx * gridDim.y;
    int bflat = blockIdx.y * gx + blockIdx.x;
    int L = bflat;
    if ((nblk & 7) == 0) {
        int per = nblk >> 3;
        L = (bflat & 7) * per + (bflat >> 3);
    }
    const int m0 = (L / gx) * 128;
    const int n0 = (L % gx) * 128;

    f32x4 acc[4][4];
#pragma unroll
    for (int mi = 0; mi < 4; ++mi)
#pragma unroll
        for (int ni = 0; ni < 4; ++ni)
#pragma unroll
            for (int r = 0; r < 4; ++r) acc[mi][ni][r] = 0.f;

    const int lrow = lane & 15;
    const int ko = (lane >> 4) * 8;
    // staging geometry (wave-uniform LDS bases, per-lane global srcs)
    const int s0 = wave * 2, s1 = wave * 2 + 1;
    const int e0a = (s0 * 64 + lane) * 8, e1a = (s1 * 64 + lane) * 8;
    const int row0 = e0a >> 5, col0 = e0a & 31;
    const int row1 = e1a >> 5, col1 = e1a & 31;

    const int NT = K >> 5;
    // prologue: stage tile 0 into buffer 0
    gl2lds16(&A[(size_t)(m0 + row0) * K + col0], &lA[0][s0 * 512]);
    gl2lds16(&BT[(size_t)(n0 + row0) * K + col0], &lB[0][s0 * 512]);
    gl2lds16(&A[(size_t)(m0 + row1) * K + col1], &lA[0][s1 * 512]);
    gl2lds16(&BT[(size_t)(n0 + row1) * K + col1], &lB[0][s1 * 512]);
    __syncthreads();

    int cur = 0;
    for (int t = 0; t < NT; ++t) {
        if (t + 1 < NT) {   // prefetch next K-tile into the other buffer
            int k0 = (t + 1) << 5;
            gl2lds16(&A[(size_t)(m0 + row0) * K + k0 + col0], &lA[cur ^ 1][s0 * 512]);
            gl2lds16(&BT[(size_t)(n0 + row0) * K + k0 + col0], &lB[cur ^ 1][s0 * 512]);
            gl2lds16(&A[(size_t)(m0 + row1) * K + k0 + col1], &lA[cur ^ 1][s1 * 512]);
            gl2lds16(&BT[(size_t)(n0 + row1) * K + k0 + col1], &lB[cur ^ 1][s1 * 512]);
        }
        short8 af[4], bfr[4];
#pragma unroll
        for (int mi = 0; mi < 4; ++mi)
            af[mi] = *reinterpret_cast<const short8*>(&lA[cur][(waveM * 64 + mi * 16 + lrow) * 32 + ko]);
#pragma unroll
        for (int ni = 0; ni < 4; ++ni)
            bfr[ni] = *reinterpret_cast<const short8*>(&lB[cur][(waveN * 64 + ni * 16 + lrow) * 32 + ko]);
#pragma unroll
        for (int mi = 0; mi < 4; ++mi)
#pragma unroll
            for (int ni = 0; ni < 4; ++ni)
                acc[mi][ni] = __builtin_amdgcn_mfma_f32_16x16x32_bf16(af[mi], bfr[ni], acc[mi][ni], 0, 0, 0);
        __syncthreads();   // drains prefetch (vmcnt0) + all waves done reading cur
        cur ^= 1;
    }

    const int rquad = (lane >> 4) * 4;
    const int ccol = lane & 15;
#pragma unroll
    for (int mi = 0; mi < 4; ++mi)
#pragma unroll
        for (int ni = 0; ni < 4; ++ni) {
            int colg = n0 + waveN * 64 + ni * 16 + ccol;
            float bb = ldext(bias, colg, isbf);
#pragma unroll
            for (int r = 0; r < 4; ++r) {
                int rowg = m0 + waveM * 64 + mi * 16 + rquad + r;
                size_t idx = (size_t)rowg * N + colg;
                float v = acc[mi][ni][r] + bb;
                if (EPI == 0) {
                    ((u16*)outb)[outoff + idx] = f2b(v);
                } else if (EPI == 1) {
                    ((u16*)outb)[outoff + idx] = f2b(fast_gelu(v));
                } else if (EPI == 2) {
                    v += ldext(resb, resoff + idx, isbf);
                    stext(outb, outoff + idx, isbf, v);
                } else if (EPI == 3) {
                    v += ldext(resb, resoff + idx, isbf);
                    ((u16*)outb)[outoff + idx] = f2b(v);
                } else if (EPI == 4) {
                    v += b2f(((const u16*)resb)[resoff + idx]);
                    stext(outb, outoff + idx, isbf, v);
                } else {  // EPI == 5: hnew = v + res; write bf16(hnew) and norm2(hnew)
                    v += ldext(resb, resoff + idx, isbf);
                    ((u16*)outb)[outoff + idx] = f2b(v);
                    float y = ldext(n2w, colg, isbf) * fast_asinh(v) + ldext(n2b, colg, isbf);
                    out2[idx] = f2b(y);
                }
            }
        }
}

// ---------- neighborhood attention: thread = (pixel, head), all in registers ----------
// qkv: [P][768] bf16 (q|k|v, each 256 = 8 heads x 32). out: [P][256] bf16.
__global__ __launch_bounds__(256) void attn_k(const u16* __restrict__ qkv, u16* __restrict__ out) {
    const int t = blockIdx.x * 256 + threadIdx.x;
    const int head = t & 7;
    const int p = t >> 3;
    const int b = p >> 12;
    const int ij = p & 4095;
    const int i = ij >> 6, j = ij & 63;
    int r0 = i - 1; r0 = r0 < 0 ? 0 : (r0 > 61 ? 61 : r0);
    int c0 = j - 1; c0 = c0 < 0 ? 0 : (c0 > 61 ? 61 : c0);

    const u16* qp = qkv + (size_t)p * 768 + head * 32;
    float q[32];
#pragma unroll
    for (int ch = 0; ch < 4; ++ch)
        unpack8(*reinterpret_cast<const uint4*>(qp + ch * 8), q + ch * 8);

    const float qscale = 0.17677669529663687f;  // 32^-0.5
    int nbp[9];
    float sc[9];
#pragma unroll
    for (int dr = 0; dr < 3; ++dr)
#pragma unroll
        for (int dc = 0; dc < 3; ++dc) {
            int nb = dr * 3 + dc;
            int np_ = b * 4096 + (r0 + dr) * 64 + (c0 + dc);
            nbp[nb] = np_;
            const u16* kp = qkv + (size_t)np_ * 768 + 256 + head * 32;
            float dot = 0.f;
#pragma unroll
            for (int ch = 0; ch < 4; ++ch) {
                float kf[8];
                unpack8(*reinterpret_cast<const uint4*>(kp + ch * 8), kf);
#pragma unroll
                for (int e = 0; e < 8; ++e) dot += q[ch * 8 + e] * kf[e];
            }
            sc[nb] = dot * qscale;
        }

    float mx = sc[0];
#pragma unroll
    for (int nb = 1; nb < 9; ++nb) mx = fmaxf(mx, sc[nb]);
    float s = 0.f;
#pragma unroll
    for (int nb = 0; nb < 9; ++nb) { sc[nb] = __expf(sc[nb] - mx); s += sc[nb]; }
    float inv = 1.f / s;

    float acc[32];
#pragma unroll
    for (int e = 0; e < 32; ++e) acc[e] = 0.f;
#pragma unroll
    for (int nb = 0; nb < 9; ++nb) {
        const u16* vp = qkv + (size_t)nbp[nb] * 768 + 512 + head * 32;
        float wgt = sc[nb] * inv;
#pragma unroll
        for (int ch = 0; ch < 4; ++ch) {
            float vf[8];
            unpack8(*reinterpret_cast<const uint4*>(vp + ch * 8), vf);
#pragma unroll
            for (int e = 0; e < 8; ++e) acc[ch * 8 + e] += wgt * vf[e];
        }
    }

    u16 ob[32];
#pragma unroll
    for (int e = 0; e < 32; ++e) ob[e] = f2b(acc[e]);
    uint4* ov = reinterpret_cast<uint4*>(ob);
    uint4* og = reinterpret_cast<uint4*>(out + (size_t)p * 256 + head * 32);
#pragma unroll
    for (int ch = 0; ch < 4; ++ch) og[ch] = ov[ch];
}

extern "C" void kernel_launch(void* const* d_in, const int* in_sizes, int n_in,
                              void* d_out, int out_size, void* d_ws, size_t ws_size,
                              hipStream_t stream) {
    const void* h      = d_in[0];
    const void* qkv_w  = d_in[1];
    const void* qkv_b  = d_in[2];
    const void* proj_w = d_in[3];
    const void* proj_b = d_in[4];
    const void* n1_w   = d_in[5];
    const void* n1_b   = d_in[6];
    const void* n2_w   = d_in[7];
    const void* n2_b   = d_in[8];
    const void* w1     = d_in[9];
    const void* b1     = d_in[10];
    const void* w2     = d_in[11];
    const void* b2     = d_in[12];

    char* ws = (char*)d_ws;
    u16* WqkvT  = (u16*)(ws + 0);          // [768][256]
    u16* WprojT = (u16*)(ws + 393216);     // [256][256]
    u16* W1T    = (u16*)(ws + 524288);     // [512][256]
    u16* W2T    = (u16*)(ws + 786432);     // [256][512]
    int* Flag   = (int*)(ws + 1048576);
    char* bufs  = ws + 1049600;

    size_t avail = ws_size > 1049600 ? ws_size - 1049600 : 0;
    int CHUNK = 4096;
    if (avail >= (size_t)65536 * 2048) CHUNK = 65536;
    else if (avail >= (size_t)16384 * 2048) CHUNK = 16384;
    else if (avail >= (size_t)8192 * 2048) CHUNK = 8192;

    u16* H1 = (u16*)bufs;                          // [CHUNK][256] bf16
    u16* S  = (u16*)(bufs + (size_t)CHUNK * 512);  // [CHUNK][768] bf16

    detect_k<<<1, 256, 0, stream>>>(h, Flag);
    transpose_k<<<768, 256, 0, stream>>>(qkv_w, WqkvT, 256, 768, Flag);
    transpose_k<<<256, 256, 0, stream>>>(proj_w, WprojT, 256, 256, Flag);
    transpose_k<<<512, 256, 0, stream>>>(w1, W1T, 256, 512, Flag);
    transpose_k<<<512, 256, 0, stream>>>(w2, W2T, 512, 256, Flag);

    if (CHUNK == 65536) {
        u16* HNS = S;                               // [65536][256] bf16 (qkv dead after attn)
        u16* T   = S + (size_t)65536 * 256;         // [65536][512] bf16
        u16* N2  = (u16*)d_out;                     // scratch: normed hnew, consumed by MLP1
                                                    // before MLP2 overwrites d_out (stream-ordered)
        norm_k<<<16384, 256, 0, stream>>>(h, 0, n1_w, n1_b, H1, Flag, 0);
        // qkv = H1 @ WqkvT + b
        { dim3 g(6, 512); gemm_bt<0><<<g, 256, 0, stream>>>(H1, WqkvT, qkv_b, nullptr, 0, S, 0,
                                                            768, 256, Flag, nullptr, nullptr, nullptr); }
        attn_k<<<2048, 256, 0, stream>>>(S, H1);
        // hnew = h + attn @ WprojT + b -> HNS bf16; side: N2 = n2 o hnew
        { dim3 g(2, 512); gemm_bt<5><<<g, 256, 0, stream>>>(H1, WprojT, proj_b, h, 0, HNS, 0,
                                                            256, 256, Flag, n2_w, n2_b, N2); }
        // T = gelu(N2 @ W1T + b1)
        { dim3 g(4, 512); gemm_bt<1><<<g, 256, 0, stream>>>(N2, W1T, b1, nullptr, 0, T, 0,
                                                            512, 256, Flag, nullptr, nullptr, nullptr); }
        // out = HNS + T @ W2T + b2
        { dim3 g(2, 512); gemm_bt<4><<<g, 256, 0, stream>>>(T, W2T, b2, HNS, 0, d_out, 0,
                                                            256, 512, Flag, nullptr, nullptr, nullptr); }
    } else {
        const int NCH = 65536 / CHUNK;
        for (int c = 0; c < NCH; ++c) {
            size_t off = (size_t)c * CHUNK * 256;
            norm_k<<<CHUNK / 4, 256, 0, stream>>>(h, off, n1_w, n1_b, H1, Flag, 0);
            { dim3 g(6, CHUNK / 128);
              gemm_bt<0><<<g, 256, 0, stream>>>(H1, WqkvT, qkv_b, nullptr, 0, S, 0,
                                                768, 256, Flag, nullptr, nullptr, nullptr); }
            attn_k<<<CHUNK / 32, 256, 0, stream>>>(S, H1);
            { dim3 g(2, CHUNK / 128);
              gemm_bt<2><<<g, 256, 0, stream>>>(H1, WprojT, proj_b, h, off, d_out, off,
                                                256, 256, Flag, nullptr, nullptr, nullptr); }
        }
        for (int c = 0; c < NCH; ++c) {
            size_t off = (size_t)c * CHUNK * 256;
            norm_k<<<CHUNK / 4, 256, 0, stream>>>(d_out, off, n2_w, n2_b, H1, Flag, 0);
            { dim3 g(4, CHUNK / 128);
              gemm_bt<1><<<g, 256, 0, stream>>>(H1, W1T, b1, nullptr, 0, S, 0,
                                                512, 256, Flag, nullptr, nullptr, nullptr); }
            { dim3 g(2, CHUNK / 128);
              gemm_bt<2><<<g, 256, 0, stream>>>(S, W2T, b2, d_out, off, d_out, off,
                                                256, 512, Flag, nullptr, nullptr, nullptr); }
        }
    }
}